// Round 1
// 783.063 us; speedup vs baseline: 1.1887x; 1.1887x over previous
//
#include <hip/hip_runtime.h>

// BasicBlock: N=32, C=256, H=W=56, two 3x3 convs (stride 1, pad 1), channel
// masks, training-mode BN, residual+ReLU. fp32 I/O; convs on bf16 MFMA.
#define N_   32
#define C_   256
#define H_   56
#define W_   56
#define HW_  (H_ * W_)        // 3136
#define NHW_ (N_ * HW_)       // 100352

typedef unsigned short u16;
typedef __attribute__((ext_vector_type(8))) short short8;   // 8 bf16
typedef __attribute__((ext_vector_type(4))) float f32x4;

__device__ __forceinline__ float b2f(u16 u) {
    union { unsigned int i; float f; } v; v.i = ((unsigned int)u) << 16; return v.f;
}
__device__ __forceinline__ u16 f2b(float f) {
    union { float f; unsigned int i; } v; v.f = f;
    unsigned int r = v.i + 0x7fffu + ((v.i >> 16) & 1u);   // RNE
    return (u16)(r >> 16);
}

typedef const __attribute__((address_space(1))) unsigned int* as1_u32p;
typedef __attribute__((address_space(3))) unsigned int* as3_u32p;
__device__ __forceinline__ void gload_lds16(const u16* g, u16* l) {
    __builtin_amdgcn_global_load_lds((as1_u32p)g, (as3_u32p)l, 16, 0, 0);
}

// ---------------------------------------------------------------------------
// x (fp32 NCHW) -> xb (bf16 NHWC). Block = (n,h); LDS transpose, pad 57.
extern "C" __global__ __launch_bounds__(256) void cvt_x_kernel(
    const float* __restrict__ x, u16* __restrict__ xb)
{
    __shared__ float t[64 * 57];
    const int nh = blockIdx.x, n = nh / H_, h = nh % H_;
    for (int cb = 0; cb < 4; ++cb) {
        __syncthreads();
        for (int idx = threadIdx.x; idx < 64 * 56; idx += 256) {
            int cc = idx / 56, w = idx % 56;
            t[cc * 57 + w] = x[(((size_t)(n * C_ + cb * 64 + cc)) * H_ + h) * W_ + w];
        }
        __syncthreads();
        for (int idx = threadIdx.x; idx < 56 * 64; idx += 256) {
            int w = idx >> 6, cc = idx & 63;
            xb[(((size_t)(n * H_ + h) * W_) + w) * C_ + cb * 64 + cc] = f2b(t[cc * 57 + w]);
        }
    }
}

// ---------------------------------------------------------------------------
// W [co][ci][3][3] fp32 -> wpA [rs][cih 8][cog 16][l15 16][lq 4][j 8] bf16.
// A wave's A-frag load for (rs, ci-half, cog) is then 1 KB fully contiguous.
extern "C" __global__ __launch_bounds__(256) void pack_w_kernel(
    const float* __restrict__ w, u16* __restrict__ wp)
{
    int o = blockIdx.x * 256 + threadIdx.x;      // grid 2304 -> 589824
    int j = o & 7, lq = (o >> 3) & 3, l15 = (o >> 5) & 15;
    int cog = (o >> 9) & 15, cih = (o >> 13) & 7, rs = o >> 16;
    int co = cog * 16 + l15;
    int ci = cih * 32 + lq * 8 + j;
    wp[o] = f2b(w[((size_t)co * C_ + ci) * 9 + rs]);
}

// ---------------------------------------------------------------------------
// Implicit-GEMM 3x3 conv on MFMA. Grid (896, 2): x = n*28 + hb (2-row pair),
// y = 128-co block. 4 waves: wave>>1 = co half, wave&1 = output row.
// Wave tile 64co x 64px = 4x4 grid of mfma_f32_16x16x32_bf16.
//
// Round-6 restructure: double-buffered 32-ci chunks. K is processed as
// 8 chunks (q = cc*2+kk) of 32 ci; each chunk's pixel tile (232 rows x 32 ci
// = 14.5 KB) is staged into lds[q&1] while the PREVIOUS chunk computes, so
// the vmcnt(0) drain at the barrier is hidden under 9 rs-steps x 16 MFMA.
// Old structure (stage -> barrier -> compute per 64-ci cc) exposed the full
// stage latency 4x per block: MfmaUtil was 16.8% with HBM at 9% (pure
// latency stall). Total LDS footprint unchanged (2 x 15360 B = 30720 B).
//
// LDS rows are 4 octs of 16 B, XOR-swizzled by (slot&3); swizzle is baked
// into each lane's GLOBAL address (LDS dest of global_load_lds is
// wave-uniform base + lane*16). Verified balance: 8 lanes per 4-bank group
// = wave64 b128 structural minimum (same as old 8-oct layout; conflicts=0).
// Halo/OOB lanes read from a DEDICATED zeroed scratch (must overlap nothing —
// round-5 bug: it aliased BN scale/shift, whose fp32 bit patterns read as
// bf16 included inf/NaN). A-frags prefetched 2 steps deep from packed wpA
// (L2-resident); prefetch indices wrap across chunks and stay in-bounds.
extern "C" __global__ __launch_bounds__(256, 4) void BasicBlock_4355096838467_kernel(
    const u16* __restrict__ xb,     // [N][56][56][256] bf16
    const u16* __restrict__ wpA,    // packed weights
    const float* __restrict__ mask,
    const u16* __restrict__ zeropad,
    u16* __restrict__ outb)         // [N][56][56][256] bf16
{
    __shared__ u16 lds[2][240 * 32];   // 2 x 15360 B double buffer

    const int tid  = threadIdx.x;
    const int wave = tid >> 6, lane = tid & 63;
    const int l15  = lane & 15, lq = lane >> 4;
    const int wave_co = wave >> 1, wave_px = wave & 1;
    const int n = blockIdx.x / 28, hb = blockIdx.x % 28;
    const int h0 = hb * 2;
    const int cog_base = blockIdx.y * 8 + wave_co * 4;
    const size_t abase0 = (size_t)cog_base * 512 + (size_t)(l15 * 32 + lq * 8);

    f32x4 acc[4][4];
#pragma unroll
    for (int i = 0; i < 4; ++i)
#pragma unroll
        for (int j = 0; j < 4; ++j) acc[i][j] = (f32x4){0.f, 0.f, 0.f, 0.f};

    // stage chunk q (32 ci) into lds[b]: 232 pixel-rows (4 halo rows x 58
    // slots) x 4 octs = 928 lane-slots; 15 wave-instructions (960 slots, the
    // 32-slot tail is pointed at zeropad -> zeroes LDS slack rows 232..239).
    auto stage = [&](int q, int b) {
        const int c0 = q * 32;
        for (int is = wave; is < 15; is += 4) {
            int L = is * 64 + lane;            // 0..959
            int pixel = L >> 2, so = L & 3;    // LDS layout index
            int rr = pixel / 58, slot = pixel - rr * 58;
            int oct = so ^ (slot & 3);         // global ci-oct for this slot
            int row = h0 - 1 + rr, col = slot - 1;
            bool ok = pixel < 232 &&
                      (unsigned)row < (unsigned)H_ && (unsigned)col < (unsigned)W_;
            const u16* gp = ok
                ? xb + (((size_t)(n * H_ + row) * W_ + col) << 8) + c0 + oct * 8
                : zeropad + oct * 8;
            gload_lds16(gp, &lds[b][is * 512]);
        }
    };

    short8 afq[3][4];
    auto loadA = [&](int rs_, size_t cb, short8 dst[4]) {
        const size_t bb = (size_t)rs_ * 65536 + cb;
#pragma unroll
        for (int fm = 0; fm < 4; ++fm)
            dst[fm] = *(const short8*)(wpA + bb + (size_t)fm * 512);
    };

    stage(0, 0);
    __syncthreads();                      // only chunk 0's latency is exposed
    loadA(0, abase0, afq[0]);
    loadA(1, abase0, afq[1]);

    for (int q = 0; q < 8; ++q) {
        const u16* Lb = &lds[q & 1][0];
        if (q < 7) stage(q + 1, (q + 1) & 1);   // overlaps with compute below
        const size_t baseq = abase0 + (size_t)q * 8192;
#pragma unroll
        for (int rs = 0; rs < 9; ++rs) {
            // prefetch A-frags 2 steps ahead (wraps into next chunk; at
            // q==7,rs>=7 this reads in-bounds garbage that is never used)
            if (rs < 7) loadA(rs + 2, baseq, afq[(rs + 2) % 3]);
            else        loadA(rs - 7, baseq + 8192, afq[(rs + 2) % 3]);
            const int r = rs / 3, s = rs - (rs / 3) * 3;
            short8 bf[4];
#pragma unroll
            for (int fn = 0; fn < 4; ++fn) {
                int slot = fn * 16 + l15 + s;
                int pixel = (wave_px + r) * 58 + slot;
                int so = lq ^ (slot & 3);
                bf[fn] = *(const short8*)(Lb + pixel * 32 + so * 8);
            }
#pragma unroll
            for (int fm = 0; fm < 4; ++fm)
#pragma unroll
                for (int fn = 0; fn < 4; ++fn)
                    acc[fm][fn] = __builtin_amdgcn_mfma_f32_16x16x32_bf16(
                        afq[rs % 3][fm], bf[fn], acc[fm][fn], 0, 0, 0);
        }
        // barrier: (a) stage(q+1) complete (vmcnt drain hidden under the 9
        // rs-steps above), (b) all waves done reading lds[q&1] before q+2
        // overwrites it. Last chunk needs none.
        if (q < 7) __syncthreads();
    }

    // epilogue: C/D col=lane&15 (pixel), row=lq*4+reg (co). mask folded.
    const int row = h0 + wave_px;
#pragma unroll
    for (int fn = 0; fn < 4; ++fn) {
        int px = fn * 16 + l15;
        if (px < W_) {
#pragma unroll
            for (int fm = 0; fm < 4; ++fm) {
                int co_b = cog_base * 16 + fm * 16 + lq * 4;
                const f32x4 mk = *(const f32x4*)(mask + co_b);
                size_t base = (((size_t)(n * H_ + row) * W_ + px) << 8) + co_b;
                ushort4 o;
                o.x = f2b(acc[fm][fn][0] * mk[0]);
                o.y = f2b(acc[fm][fn][1] * mk[1]);
                o.z = f2b(acc[fm][fn][2] * mk[2]);
                o.w = f2b(acc[fm][fn][3] * mk[3]);
                *(ushort4*)(outb + base) = o;
            }
        }
    }
}

// ---------------------------------------------------------------------------
// zero stats accumulators + scale/shift + zeropad scratch (12 KB). grid 12.
extern "C" __global__ void zero_accum_kernel(float* __restrict__ p) {
    p[blockIdx.x * 256 + threadIdx.x] = 0.f;
}

// Per-channel sum/sumsq over NHWC bf16 via block partials + atomics. grid 392.
extern "C" __global__ __launch_bounds__(256) void stats_nhwc_kernel(
    const u16* __restrict__ hb, float* __restrict__ gsum, float* __restrict__ gsq)
{
    __shared__ float s_s[8 * 256];
    __shared__ float s_q[8 * 256];
    const int g = threadIdx.x >> 5, l = threadIdx.x & 31;
    float s[8], q[8];
#pragma unroll
    for (int j = 0; j < 8; ++j) { s[j] = 0.f; q[j] = 0.f; }
    const int pbase = blockIdx.x * 256;
    for (int t = 0; t < 32; ++t) {
        int p = pbase + g + t * 8;
        short8 v = *(const short8*)(hb + (size_t)p * C_ + l * 8);
#pragma unroll
        for (int j = 0; j < 8; ++j) {
            float f = b2f((u16)v[j]);
            s[j] += f; q[j] += f * f;
        }
    }
#pragma unroll
    for (int j = 0; j < 8; ++j) {
        s_s[g * 256 + l * 8 + j] = s[j];
        s_q[g * 256 + l * 8 + j] = q[j];
    }
    __syncthreads();
    const int c = threadIdx.x;
    float S = 0.f, Q = 0.f;
#pragma unroll
    for (int g2 = 0; g2 < 8; ++g2) { S += s_s[g2 * 256 + c]; Q += s_q[g2 * 256 + c]; }
    atomicAdd(&gsum[c], S);
    atomicAdd(&gsq[c], Q);
}

// scale/shift from accumulated stats. 1 block x 256.
extern "C" __global__ void finalize_bn_kernel(
    const float* __restrict__ gsum, const float* __restrict__ gsq,
    const float* __restrict__ gamma, const float* __restrict__ beta,
    float* __restrict__ scale, float* __restrict__ shift)
{
    const int c = threadIdx.x;
    const float inv_n = 1.f / (float)NHW_;
    float mean = gsum[c] * inv_n;
    float var  = gsq[c] * inv_n - mean * mean;
    var = fmaxf(var, 0.f);
    float inv = rsqrtf(var + 1e-5f);
    float sc = gamma[c] * inv;
    scale[c] = sc;
    shift[c] = beta[c] - mean * sc;
}

// In-place BN+ReLU on NHWC bf16. grid 12544, 8 elems/thread.
extern "C" __global__ __launch_bounds__(256) void bn_relu_nhwc_kernel(
    u16* __restrict__ hb, const float* __restrict__ scale, const float* __restrict__ shift)
{
    size_t idx = ((size_t)blockIdx.x * 256 + threadIdx.x) * 8;
    int c0 = (int)(idx & 255);
    short8 v = *(short8*)(hb + idx);
    short8 o;
#pragma unroll
    for (int j = 0; j < 8; ++j) {
        int c = c0 + j;
        float f = b2f((u16)v[j]) * scale[c] + shift[c];
        o[j] = (short)f2b(fmaxf(f, 0.f));
    }
    *(short8*)(hb + idx) = o;
}

// out = relu(bn2(h2) + x): NHWC bf16 -> NCHW fp32 via LDS transpose. grid (n,h).
extern "C" __global__ __launch_bounds__(256) void bn_add_relu_out_kernel(
    const u16* __restrict__ h2b, const float* __restrict__ x,
    const float* __restrict__ scale, const float* __restrict__ shift,
    float* __restrict__ out)
{
    __shared__ float t[64 * 57];
    const int nh = blockIdx.x, n = nh / H_, h = nh % H_;
    const size_t pixbase = ((size_t)(n * H_ + h) * W_) << 8;
    for (int cb = 0; cb < 4; ++cb) {
        __syncthreads();
        for (int it = threadIdx.x; it < 448; it += 256) {      // 56 px * 8 octs
            int w = it >> 3, oc = it & 7;
            short8 v = *(const short8*)(h2b + pixbase + ((size_t)w << 8) + cb * 64 + oc * 8);
#pragma unroll
            for (int j = 0; j < 8; ++j) t[(oc * 8 + j) * 57 + w] = b2f((u16)v[j]);
        }
        __syncthreads();
        for (int it = threadIdx.x; it < 64 * 56; it += 256) {
            int cl = it / 56, w = it % 56;
            int c = cb * 64 + cl;
            size_t oidx = ((size_t)(n * C_ + c) * H_ + h) * W_ + w;
            float v = t[cl * 57 + w] * scale[c] + shift[c] + x[oidx];
            out[oidx] = fmaxf(v, 0.f);
        }
    }
}

// ---------------------------------------------------------------------------
extern "C" void kernel_launch(void* const* d_in, const int* in_sizes, int n_in,
                              void* d_out, int out_size, void* d_ws, size_t ws_size,
                              hipStream_t stream) {
    const float* x      = (const float*)d_in[0];
    const float* W1     = (const float*)d_in[1];
    const float* W2     = (const float*)d_in[2];
    const float* gamma1 = (const float*)d_in[3];
    const float* beta1  = (const float*)d_in[4];
    const float* gamma2 = (const float*)d_in[5];
    const float* beta2  = (const float*)d_in[6];
    const float* mask1  = (const float*)d_in[7];
    const float* mask2  = (const float*)d_in[8];
    float* out = (float*)d_out;

    // ws layout (NO overlaps — round-5 bug was zeropad aliasing scale/shift):
    // [0,4K)   stats accumulators (gsum1,gsq1,gsum2,gsq2)
    // [4K,8K)  scale1,shift1,scale2,shift2
    // [8K,12K) zeropad scratch (zeroed every launch, read-only thereafter)
    // [12K,..) Wp1 | Wp2 | xb (reused as h2b)
    char* ws = (char*)d_ws;
    float* gsum1  = (float*)ws;
    float* gsq1   = gsum1 + 256;
    float* gsum2  = gsq1 + 256;
    float* gsq2   = gsum2 + 256;
    float* scale1 = gsq2 + 256;
    float* shift1 = scale1 + 256;
    float* scale2 = shift1 + 256;
    float* shift2 = scale2 + 256;
    u16* zeropad = (u16*)(ws + 8192);
    u16* Wp1 = (u16*)(ws + 12288);
    u16* Wp2 = Wp1 + 9 * 256 * 256;
    u16* xb  = Wp2 + 9 * 256 * 256;
    u16* h2b = xb;                          // xb dead after conv1
    u16* h1b = (u16*)d_out;                 // bf16 scratch inside 102.8 MB output

    zero_accum_kernel<<<dim3(12), dim3(256), 0, stream>>>(gsum1);  // stats+scales+zeropad
    cvt_x_kernel<<<dim3(N_ * H_), dim3(256), 0, stream>>>(x, xb);
    pack_w_kernel<<<dim3(2304), dim3(256), 0, stream>>>(W1, Wp1);
    pack_w_kernel<<<dim3(2304), dim3(256), 0, stream>>>(W2, Wp2);

    dim3 cgrid(N_ * 28, 2);
    BasicBlock_4355096838467_kernel<<<cgrid, dim3(256), 0, stream>>>(xb, Wp1, mask1, zeropad, h1b);
    stats_nhwc_kernel<<<dim3(392), dim3(256), 0, stream>>>(h1b, gsum1, gsq1);
    finalize_bn_kernel<<<dim3(1), dim3(256), 0, stream>>>(gsum1, gsq1, gamma1, beta1, scale1, shift1);
    bn_relu_nhwc_kernel<<<dim3(12544), dim3(256), 0, stream>>>(h1b, scale1, shift1);

    BasicBlock_4355096838467_kernel<<<cgrid, dim3(256), 0, stream>>>(h1b, Wp2, mask2, zeropad, h2b);
    stats_nhwc_kernel<<<dim3(392), dim3(256), 0, stream>>>(h2b, gsum2, gsq2);
    finalize_bn_kernel<<<dim3(1), dim3(256), 0, stream>>>(gsum2, gsq2, gamma2, beta2, scale2, shift2);
    bn_add_relu_out_kernel<<<dim3(N_ * H_), dim3(256), 0, stream>>>(h2b, x, scale2, shift2, out);
}

// Round 2
// 751.045 us; speedup vs baseline: 1.2394x; 1.0426x over previous
//
#include <hip/hip_runtime.h>

// BasicBlock: N=32, C=256, H=W=56, two 3x3 convs (stride 1, pad 1), channel
// masks, training-mode BN, residual+ReLU. fp32 I/O; convs on bf16 MFMA.
//
// Activations live in CHUNK-MAJOR bf16 layout: [8 planes][N*H*W][32 ci].
// Round-1 lesson: 32-ci staging chunks over NHWC read 64-B half-lines whose
// other half was evicted before its turn -> FETCH_SIZE 3.2x (436 MB). With
// plane-major layout every chunk stages full 128-B lines.
#define N_   32
#define C_   256
#define H_   56
#define W_   56
#define HW_  (H_ * W_)        // 3136
#define NHW_ (N_ * HW_)       // 100352
#define PLANE_ ((size_t)NHW_ * 32)   // u16 elems per 32-ci plane

typedef unsigned short u16;
typedef __attribute__((ext_vector_type(8))) short short8;   // 8 bf16
typedef __attribute__((ext_vector_type(4))) float f32x4;

__device__ __forceinline__ float b2f(u16 u) {
    union { unsigned int i; float f; } v; v.i = ((unsigned int)u) << 16; return v.f;
}
__device__ __forceinline__ u16 f2b(float f) {
    union { float f; unsigned int i; } v; v.f = f;
    unsigned int r = v.i + 0x7fffu + ((v.i >> 16) & 1u);   // RNE
    return (u16)(r >> 16);
}

typedef const __attribute__((address_space(1))) unsigned int* as1_u32p;
typedef __attribute__((address_space(3))) unsigned int* as3_u32p;
__device__ __forceinline__ void gload_lds16(const u16* g, u16* l) {
    __builtin_amdgcn_global_load_lds((as1_u32p)g, (as3_u32p)l, 16, 0, 0);
}

// ---------------------------------------------------------------------------
// x (fp32 NCHW) -> xb (bf16 chunk-major). Block = (n,h); LDS transpose.
extern "C" __global__ __launch_bounds__(256) void cvt_x_kernel(
    const float* __restrict__ x, u16* __restrict__ xb)
{
    __shared__ float t[64 * 57];
    const int nh = blockIdx.x, n = nh / H_, h = nh % H_;
    const size_t pix0 = (size_t)(n * H_ + h) * W_;
    for (int cb = 0; cb < 4; ++cb) {
        __syncthreads();
        for (int idx = threadIdx.x; idx < 64 * 56; idx += 256) {
            int cc = idx / 56, w = idx % 56;
            t[cc * 57 + w] = x[(((size_t)(n * C_ + cb * 64 + cc)) * H_ + h) * W_ + w];
        }
        __syncthreads();
        for (int idx = threadIdx.x; idx < 56 * 64; idx += 256) {
            int w = idx >> 6, cc = idx & 63;
            int plane = cb * 2 + (cc >> 5);
            xb[(size_t)plane * PLANE_ + (pix0 + w) * 32 + (cc & 31)] = f2b(t[cc * 57 + w]);
        }
    }
}

// ---------------------------------------------------------------------------
// W [co][ci][3][3] fp32 -> wpA [rs][cih 8][cog 16][l15 16][lq 4][j 8] bf16.
// A wave's A-frag load for (rs, ci-half, cog) is then 1 KB fully contiguous.
extern "C" __global__ __launch_bounds__(256) void pack_w_kernel(
    const float* __restrict__ w, u16* __restrict__ wp)
{
    int o = blockIdx.x * 256 + threadIdx.x;      // grid 2304 -> 589824
    int j = o & 7, lq = (o >> 3) & 3, l15 = (o >> 5) & 15;
    int cog = (o >> 9) & 15, cih = (o >> 13) & 7, rs = o >> 16;
    int co = cog * 16 + l15;
    int ci = cih * 32 + lq * 8 + j;
    wp[o] = f2b(w[((size_t)co * C_ + ci) * 9 + rs]);
}

// ---------------------------------------------------------------------------
// Implicit-GEMM 3x3 conv on MFMA. Grid (896, 2): x (XCD-swizzled) = n*28 + hb
// (2-row pair), y = 128-co block. 4 waves: wave>>1 = co half, wave&1 = row.
// Wave tile 64co x 64px = 4x4 grid of mfma_f32_16x16x32_bf16.
//
// Double-buffered 32-ci chunks (8 chunks), stage(q+1) issued before the 9
// rs-steps computing chunk q so the barrier's vmcnt drain is hidden under
// 144 MFMA. LDS rows = 4 octs of 16 B, XOR-swizzled by ((slot>>1)&3) --
// round-1's (slot&3) swizzle correlated so-parity with pixel-parity and gave
// a 4-way bank conflict (8.26M); (slot>>1) makes (pixel&1, so) a bijection
// of slot mod 8 -> all 32 banks covered, conflict-free. Swizzle is baked
// into each lane's GLOBAL address (LDS dest of global_load_lds is
// wave-uniform base + lane*16).
// Halo/OOB lanes read from a DEDICATED zeroed scratch (must overlap nothing —
// round-5 bug: it aliased BN scale/shift, whose fp32 bit patterns read as
// bf16 included inf/NaN). A-frags prefetched 2 steps deep from packed wpA.
extern "C" __global__ __launch_bounds__(256, 4) void BasicBlock_4355096838467_kernel(
    const u16* __restrict__ xb,     // chunk-major [8][NHW][32] bf16
    const u16* __restrict__ wpA,    // packed weights
    const float* __restrict__ mask,
    const u16* __restrict__ zeropad,
    u16* __restrict__ outb)         // chunk-major [8][NHW][32] bf16
{
    __shared__ u16 lds[2][240 * 32];   // 2 x 15360 B double buffer

    const int tid  = threadIdx.x;
    const int wave = tid >> 6, lane = tid & 63;
    const int l15  = lane & 15, lq = lane >> 4;
    const int wave_co = wave >> 1, wave_px = wave & 1;
    // XCD-contiguous bijection: 896 = 8 XCD * 112; adjacent hb share 2 of 4
    // halo rows -> same-XCD L2 hits instead of cross-die refetch.
    const int sb = (blockIdx.x & 7) * 112 + (blockIdx.x >> 3);
    const int n = sb / 28, hb = sb % 28;
    const int h0 = hb * 2;
    const int cog_base = blockIdx.y * 8 + wave_co * 4;
    const size_t abase0 = (size_t)cog_base * 512 + (size_t)(l15 * 32 + lq * 8);

    f32x4 acc[4][4];
#pragma unroll
    for (int i = 0; i < 4; ++i)
#pragma unroll
        for (int j = 0; j < 4; ++j) acc[i][j] = (f32x4){0.f, 0.f, 0.f, 0.f};

    // stage chunk q (32 ci) into lds[b]: 232 pixel-rows (4 halo rows x 58
    // slots) x 4 octs = 928 lane-slots; 15 wave-instructions (960 slots, the
    // 32-slot tail is pointed at zeropad -> zeroes LDS slack rows 232..239).
    auto stage = [&](int q, int b) {
        const u16* plane = xb + (size_t)q * PLANE_;
        for (int is = wave; is < 15; is += 4) {
            int L = is * 64 + lane;            // 0..959
            int pixel = L >> 2, so = L & 3;    // LDS layout index
            int rr = pixel / 58, slot = pixel - rr * 58;
            int oct = so ^ ((slot >> 1) & 3);  // global ci-oct for this slot
            int row = h0 - 1 + rr, col = slot - 1;
            bool ok = pixel < 232 &&
                      (unsigned)row < (unsigned)H_ && (unsigned)col < (unsigned)W_;
            const u16* gp = ok
                ? plane + ((size_t)(n * H_ + row) * W_ + col) * 32 + oct * 8
                : zeropad + oct * 8;
            gload_lds16(gp, &lds[b][is * 512]);
        }
    };

    short8 afq[3][4];
    auto loadA = [&](int rs_, size_t cb, short8 dst[4]) {
        const size_t bb = (size_t)rs_ * 65536 + cb;
#pragma unroll
        for (int fm = 0; fm < 4; ++fm)
            dst[fm] = *(const short8*)(wpA + bb + (size_t)fm * 512);
    };

    stage(0, 0);
    __syncthreads();                      // only chunk 0's latency is exposed
    loadA(0, abase0, afq[0]);
    loadA(1, abase0, afq[1]);

    for (int q = 0; q < 8; ++q) {
        const u16* Lb = &lds[q & 1][0];
        if (q < 7) stage(q + 1, (q + 1) & 1);   // overlaps with compute below
        const size_t baseq = abase0 + (size_t)q * 8192;
#pragma unroll
        for (int rs = 0; rs < 9; ++rs) {
            // prefetch A-frags 2 steps ahead (wraps into next chunk; at
            // q==7,rs>=7 this reads in-bounds garbage that is never used)
            if (rs < 7) loadA(rs + 2, baseq, afq[(rs + 2) % 3]);
            else        loadA(rs - 7, baseq + 8192, afq[(rs + 2) % 3]);
            const int r = rs / 3, s = rs - (rs / 3) * 3;
            short8 bf[4];
#pragma unroll
            for (int fn = 0; fn < 4; ++fn) {
                int slot = fn * 16 + l15 + s;
                int pixel = (wave_px + r) * 58 + slot;
                int so = lq ^ ((slot >> 1) & 3);
                bf[fn] = *(const short8*)(Lb + pixel * 32 + so * 8);
            }
#pragma unroll
            for (int fm = 0; fm < 4; ++fm)
#pragma unroll
                for (int fn = 0; fn < 4; ++fn)
                    acc[fm][fn] = __builtin_amdgcn_mfma_f32_16x16x32_bf16(
                        afq[rs % 3][fm], bf[fn], acc[fm][fn], 0, 0, 0);
        }
        // barrier: (a) stage(q+1) complete (vmcnt drain hidden under the 9
        // rs-steps above), (b) all waves done reading lds[q&1] before q+2
        // overwrites it. Last chunk needs none.
        if (q < 7) __syncthreads();
    }

    // epilogue: C/D col=lane&15 (pixel), row=lq*4+reg (co). mask folded.
    // chunk-major store: plane = co>>5, 8-B ushort4 at (co&31).
    const int row = h0 + wave_px;
#pragma unroll
    for (int fn = 0; fn < 4; ++fn) {
        int px = fn * 16 + l15;
        if (px < W_) {
#pragma unroll
            for (int fm = 0; fm < 4; ++fm) {
                int co_b = cog_base * 16 + fm * 16 + lq * 4;
                const f32x4 mk = *(const f32x4*)(mask + co_b);
                size_t base = (size_t)(co_b >> 5) * PLANE_
                            + ((size_t)(n * H_ + row) * W_ + px) * 32 + (co_b & 31);
                ushort4 o;
                o.x = f2b(acc[fm][fn][0] * mk[0]);
                o.y = f2b(acc[fm][fn][1] * mk[1]);
                o.z = f2b(acc[fm][fn][2] * mk[2]);
                o.w = f2b(acc[fm][fn][3] * mk[3]);
                *(ushort4*)(outb + base) = o;
            }
        }
    }
}

// ---------------------------------------------------------------------------
// zero stats accumulators + scale/shift + zeropad scratch (12 KB). grid 12.
extern "C" __global__ void zero_accum_kernel(float* __restrict__ p) {
    p[blockIdx.x * 256 + threadIdx.x] = 0.f;
}

// Per-channel sum/sumsq over chunk-major bf16 via block partials + atomics.
// grid 392. Logical channel for lane l, elem j is still 8*l+j (the plane
// decomposition (l>>2)*32 + (l&3)*8 + j == 8l+j), so only addresses change.
extern "C" __global__ __launch_bounds__(256) void stats_nhwc_kernel(
    const u16* __restrict__ hb, float* __restrict__ gsum, float* __restrict__ gsq)
{
    __shared__ float s_s[8 * 256];
    __shared__ float s_q[8 * 256];
    const int g = threadIdx.x >> 5, l = threadIdx.x & 31;
    const size_t pbase_off = (size_t)(l >> 2) * PLANE_ + (l & 3) * 8;
    float s[8], q[8];
#pragma unroll
    for (int j = 0; j < 8; ++j) { s[j] = 0.f; q[j] = 0.f; }
    const int pbase = blockIdx.x * 256;
    for (int t = 0; t < 32; ++t) {
        int p = pbase + g + t * 8;
        short8 v = *(const short8*)(hb + pbase_off + (size_t)p * 32);
#pragma unroll
        for (int j = 0; j < 8; ++j) {
            float f = b2f((u16)v[j]);
            s[j] += f; q[j] += f * f;
        }
    }
#pragma unroll
    for (int j = 0; j < 8; ++j) {
        s_s[g * 256 + l * 8 + j] = s[j];
        s_q[g * 256 + l * 8 + j] = q[j];
    }
    __syncthreads();
    const int c = threadIdx.x;
    float S = 0.f, Q = 0.f;
#pragma unroll
    for (int g2 = 0; g2 < 8; ++g2) { S += s_s[g2 * 256 + c]; Q += s_q[g2 * 256 + c]; }
    atomicAdd(&gsum[c], S);
    atomicAdd(&gsq[c], Q);
}

// scale/shift from accumulated stats. 1 block x 256.
extern "C" __global__ void finalize_bn_kernel(
    const float* __restrict__ gsum, const float* __restrict__ gsq,
    const float* __restrict__ gamma, const float* __restrict__ beta,
    float* __restrict__ scale, float* __restrict__ shift)
{
    const int c = threadIdx.x;
    const float inv_n = 1.f / (float)NHW_;
    float mean = gsum[c] * inv_n;
    float var  = gsq[c] * inv_n - mean * mean;
    var = fmaxf(var, 0.f);
    float inv = rsqrtf(var + 1e-5f);
    float sc = gamma[c] * inv;
    scale[c] = sc;
    shift[c] = beta[c] - mean * sc;
}

// In-place BN+ReLU on chunk-major bf16. grid 12544 (= 8 planes x 1568),
// 8 elems/thread; channel = plane*32 + (idx&31) + j.
extern "C" __global__ __launch_bounds__(256) void bn_relu_nhwc_kernel(
    u16* __restrict__ hb, const float* __restrict__ scale, const float* __restrict__ shift)
{
    size_t idx = ((size_t)blockIdx.x * 256 + threadIdx.x) * 8;
    int c0 = (int)(blockIdx.x / 1568) * 32 + (int)(idx & 31);
    short8 v = *(short8*)(hb + idx);
    short8 o;
#pragma unroll
    for (int j = 0; j < 8; ++j) {
        int c = c0 + j;
        float f = b2f((u16)v[j]) * scale[c] + shift[c];
        o[j] = (short)f2b(fmaxf(f, 0.f));
    }
    *(short8*)(hb + idx) = o;
}

// out = relu(bn2(h2) + x): chunk-major bf16 -> NCHW fp32 via LDS transpose.
// grid (n,h); oc 0..7 maps to plane 2*cb+(oc>>2), oct (oc&3).
extern "C" __global__ __launch_bounds__(256) void bn_add_relu_out_kernel(
    const u16* __restrict__ h2b, const float* __restrict__ x,
    const float* __restrict__ scale, const float* __restrict__ shift,
    float* __restrict__ out)
{
    __shared__ float t[64 * 57];
    const int nh = blockIdx.x, n = nh / H_, h = nh % H_;
    const size_t pix0 = (size_t)(n * H_ + h) * W_;
    for (int cb = 0; cb < 4; ++cb) {
        __syncthreads();
        for (int it = threadIdx.x; it < 448; it += 256) {      // 56 px * 8 octs
            int w = it >> 3, oc = it & 7;
            size_t addr = (size_t)(cb * 2 + (oc >> 2)) * PLANE_
                        + (pix0 + w) * 32 + (oc & 3) * 8;
            short8 v = *(const short8*)(h2b + addr);
#pragma unroll
            for (int j = 0; j < 8; ++j) t[(oc * 8 + j) * 57 + w] = b2f((u16)v[j]);
        }
        __syncthreads();
        for (int it = threadIdx.x; it < 64 * 56; it += 256) {
            int cl = it / 56, w = it % 56;
            int c = cb * 64 + cl;
            size_t oidx = ((size_t)(n * C_ + c) * H_ + h) * W_ + w;
            float v = t[cl * 57 + w] * scale[c] + shift[c] + x[oidx];
            out[oidx] = fmaxf(v, 0.f);
        }
    }
}

// ---------------------------------------------------------------------------
extern "C" void kernel_launch(void* const* d_in, const int* in_sizes, int n_in,
                              void* d_out, int out_size, void* d_ws, size_t ws_size,
                              hipStream_t stream) {
    const float* x      = (const float*)d_in[0];
    const float* W1     = (const float*)d_in[1];
    const float* W2     = (const float*)d_in[2];
    const float* gamma1 = (const float*)d_in[3];
    const float* beta1  = (const float*)d_in[4];
    const float* gamma2 = (const float*)d_in[5];
    const float* beta2  = (const float*)d_in[6];
    const float* mask1  = (const float*)d_in[7];
    const float* mask2  = (const float*)d_in[8];
    float* out = (float*)d_out;

    // ws layout (NO overlaps — round-5 bug was zeropad aliasing scale/shift):
    // [0,4K)   stats accumulators (gsum1,gsq1,gsum2,gsq2)
    // [4K,8K)  scale1,shift1,scale2,shift2
    // [8K,12K) zeropad scratch (zeroed every launch, read-only thereafter)
    // [12K,..) Wp1 | Wp2 | xb (reused as h2b)
    char* ws = (char*)d_ws;
    float* gsum1  = (float*)ws;
    float* gsq1   = gsum1 + 256;
    float* gsum2  = gsq1 + 256;
    float* gsq2   = gsum2 + 256;
    float* scale1 = gsq2 + 256;
    float* shift1 = scale1 + 256;
    float* scale2 = shift1 + 256;
    float* shift2 = scale2 + 256;
    u16* zeropad = (u16*)(ws + 8192);
    u16* Wp1 = (u16*)(ws + 12288);
    u16* Wp2 = Wp1 + 9 * 256 * 256;
    u16* xb  = Wp2 + 9 * 256 * 256;
    u16* h2b = xb;                          // xb dead after conv1
    u16* h1b = (u16*)d_out;                 // bf16 scratch inside 102.8 MB output

    zero_accum_kernel<<<dim3(12), dim3(256), 0, stream>>>(gsum1);  // stats+scales+zeropad
    cvt_x_kernel<<<dim3(N_ * H_), dim3(256), 0, stream>>>(x, xb);
    pack_w_kernel<<<dim3(2304), dim3(256), 0, stream>>>(W1, Wp1);
    pack_w_kernel<<<dim3(2304), dim3(256), 0, stream>>>(W2, Wp2);

    dim3 cgrid(N_ * 28, 2);
    BasicBlock_4355096838467_kernel<<<cgrid, dim3(256), 0, stream>>>(xb, Wp1, mask1, zeropad, h1b);
    stats_nhwc_kernel<<<dim3(392), dim3(256), 0, stream>>>(h1b, gsum1, gsq1);
    finalize_bn_kernel<<<dim3(1), dim3(256), 0, stream>>>(gsum1, gsq1, gamma1, beta1, scale1, shift1);
    bn_relu_nhwc_kernel<<<dim3(12544), dim3(256), 0, stream>>>(h1b, scale1, shift1);

    BasicBlock_4355096838467_kernel<<<cgrid, dim3(256), 0, stream>>>(h1b, Wp2, mask2, zeropad, h2b);
    stats_nhwc_kernel<<<dim3(392), dim3(256), 0, stream>>>(h2b, gsum2, gsq2);
    finalize_bn_kernel<<<dim3(1), dim3(256), 0, stream>>>(gsum2, gsq2, gamma2, beta2, scale2, shift2);
    bn_add_relu_out_kernel<<<dim3(N_ * H_), dim3(256), 0, stream>>>(h2b, x, scale2, shift2, out);
}

// Round 3
// 598.696 us; speedup vs baseline: 1.5548x; 1.2545x over previous
//
#include <hip/hip_runtime.h>

// BasicBlock: N=32, C=256, H=W=56, two 3x3 convs (stride 1, pad 1), channel
// masks, training-mode BN, residual+ReLU. fp32 I/O; convs on bf16 MFMA.
//
// Activations: chunk-major bf16 [8 planes][N*H*W][32 ci] (round-1 lesson:
// full 128-B lines per staging chunk). Channels PERMUTED so mask-surviving
// channels come first (round-3): conv skips MFMA for dead co-tiles and conv2
// skips provably-zero ci-chunks (device-computed qlist). Perms/qlists are
// computed on-device from the masks -> data-independent correctness.
#define N_   32
#define C_   256
#define H_   56
#define W_   56
#define HW_  (H_ * W_)        // 3136
#define NHW_ (N_ * HW_)       // 100352
#define PLANE_ ((size_t)NHW_ * 32)   // u16 elems per 32-ci plane

typedef unsigned short u16;
typedef __attribute__((ext_vector_type(8))) short short8;   // 8 bf16
typedef __attribute__((ext_vector_type(4))) float f32x4;

__device__ __forceinline__ float b2f(u16 u) {
    union { unsigned int i; float f; } v; v.i = ((unsigned int)u) << 16; return v.f;
}
__device__ __forceinline__ u16 f2b(float f) {
    union { float f; unsigned int i; } v; v.f = f;
    unsigned int r = v.i + 0x7fffu + ((v.i >> 16) & 1u);   // RNE
    return (u16)(r >> 16);
}

typedef const __attribute__((address_space(1))) unsigned int* as1_u32p;
typedef __attribute__((address_space(3))) unsigned int* as3_u32p;
__device__ __forceinline__ void gload_lds16(const u16* g, u16* l) {
    __builtin_amdgcn_global_load_lds((as1_u32p)g, (as3_u32p)l, 16, 0, 0);
}

// ---------------------------------------------------------------------------
// x (fp32 NCHW) -> xb (bf16 chunk-major). Block = (n,h); LDS transpose.
extern "C" __global__ __launch_bounds__(256) void cvt_x_kernel(
    const float* __restrict__ x, u16* __restrict__ xb)
{
    __shared__ float t[64 * 57];
    const int nh = blockIdx.x, n = nh / H_, h = nh % H_;
    const size_t pix0 = (size_t)(n * H_ + h) * W_;
    for (int cb = 0; cb < 4; ++cb) {
        __syncthreads();
        for (int idx = threadIdx.x; idx < 64 * 56; idx += 256) {
            int cc = idx / 56, w = idx % 56;
            t[cc * 57 + w] = x[(((size_t)(n * C_ + cb * 64 + cc)) * H_ + h) * W_ + w];
        }
        __syncthreads();
        for (int idx = threadIdx.x; idx < 56 * 64; idx += 256) {
            int w = idx >> 6, cc = idx & 63;
            int plane = cb * 2 + (cc >> 5);
            xb[(size_t)plane * PLANE_ + (pix0 + w) * 32 + (cc & 31)] = f2b(t[cc * 57 + w]);
        }
    }
}

// ---------------------------------------------------------------------------
// Per-mask scan: perm (survivors first), maskp (mask gathered to perm space),
// kpar = { ceil16(K), nq=8, K, 0, qlist 0..7 }. id256 = identity (for conv1 ci).
extern "C" __global__ void mask_scan_kernel(
    const float* __restrict__ mask, int* __restrict__ perm,
    float* __restrict__ maskp, int* __restrict__ kpar, int* __restrict__ id256)
{
    __shared__ float m[256];
    const int c = threadIdx.x;
    m[c] = mask[c];
    id256[c] = c;
    __syncthreads();
    int pre = 0, tot = 0;
    for (int i = 0; i < 256; ++i) {
        int nz = (m[i] != 0.f) ? 1 : 0;
        if (i < c) pre += nz;
        tot += nz;
    }
    const int nz = (m[c] != 0.f) ? 1 : 0;
    const int pos = nz ? pre : tot + (c - pre);
    perm[pos] = c;
    maskp[pos] = m[c];
    if (c == 0) {
        kpar[0] = ((tot + 15) >> 4) << 4;   // Kc: co-tiles above this are dead
        kpar[1] = 8;                        // nq (default: all chunks)
        kpar[2] = tot;                      // raw survivor count
        kpar[3] = 0;
    }
    if (c < 8) kpar[4 + c] = c;             // identity qlist
}

// conv2 ci-chunk selection: chunk q of h1 (perm1 space) is skippable iff it is
// entirely in the masked tail (ci >= K1, where h1 pre-BN == 0 exactly) AND
// relu(shift1)==0 for all its channels (then its value is exactly 0).
extern "C" __global__ void chunk_sel_kernel(
    const float* __restrict__ shift, const int* __restrict__ kparK,
    int* __restrict__ kpar)
{
    __shared__ int act[8];
    const int c = threadIdx.x;
    if (c < 8) act[c] = 0;
    __syncthreads();
    const int K = kparK[2];
    const bool a = (c < K) || (shift[c] > 0.f);
    if (a) atomicOr(&act[c >> 5], 1);
    __syncthreads();
    if (c == 0) {
        int nq = 0;
        for (int q = 0; q < 8; ++q) if (act[q]) kpar[4 + nq++] = q;
        kpar[1] = nq;
    }
}

// ---------------------------------------------------------------------------
// W [co][ci][3][3] fp32 -> wpA [rs][cih 8][cog 16][l15 16][lq 4][j 8] bf16,
// gathered through operm (output-channel perm) and iperm (input-channel perm).
extern "C" __global__ __launch_bounds__(256) void pack_w_kernel(
    const float* __restrict__ w, const int* __restrict__ operm,
    const int* __restrict__ iperm, u16* __restrict__ wp)
{
    int o = blockIdx.x * 256 + threadIdx.x;      // grid 2304 -> 589824
    int j = o & 7, lq = (o >> 3) & 3, l15 = (o >> 5) & 15;
    int cog = (o >> 9) & 15, cih = (o >> 13) & 7, rs = o >> 16;
    int co = operm[cog * 16 + l15];
    int ci = iperm[cih * 32 + lq * 8 + j];
    wp[o] = f2b(w[((size_t)co * C_ + ci) * 9 + rs]);
}

// ---------------------------------------------------------------------------
// Implicit-GEMM 3x3 conv on MFMA. 1-D grid 1792: id -> (xcd=id&7, r=id>>3),
// y = r&1 (co half), sb = xcd*112 + (r>>1) -> the two co-halves of one pixel
// tile run on the SAME XCD, adjacent in dispatch -> staging L2 reuse.
// 4 waves: wave>>1 = co quarter-within-half, wave&1 = output row.
// Wave tile 64co x 64px = 4x4 grid of mfma_f32_16x16x32_bf16.
//
// Round-3 restructure: ring-3 LDS + raw s_barrier + counted vmcnt so the
// stage queue NEVER drains (round-2 lesson: __syncthreads' vmcnt(0) drain
// made the conv latency-duty-cycle-bound at 1.65 TB/s, MfmaUtil 23%).
// Body t: [36 loadA + 9x(4 ds_read + 16 MFMA)] [stage(t+2) -> ring (t+2)%3]
// [vmcnt(3): own stage(t+1) done, stage(t+2) stays in flight] [s_barrier].
// stage is issued at body END so the compiler's per-register afq waits
// (which retire in order) never force stage(t+2) to retire.
// vmcnt(3) is exact for the min-stage-count wave (wave 3 issues 3 gloads).
//
// Mask skip: nf = live 16-co tiles for this wave (from kpar[0]); dead tiles
// skip A-loads + MFMA (acc stays 0 -> epilogue writes exact zeros via maskp).
// K-chunks iterate a device-built qlist (kpar[1], kpar[4..]): conv1 identity,
// conv2 skips provably-zero ci-chunks.
//
// LDS rows = 4 octs of 16 B, XOR-swizzled by ((slot>>1)&3) (conflict-free,
// verified round-2: SQ_LDS_BANK_CONFLICT == 0); swizzle baked into the
// GLOBAL address (LDS dest of global_load_lds is wave-uniform base+lane*16).
// Halo/OOB lanes read a DEDICATED zeroed scratch (round-5 bug: aliasing).
extern "C" __global__ __launch_bounds__(256, 3) void BasicBlock_4355096838467_kernel(
    const u16* __restrict__ xb,     // chunk-major [8][NHW][32] bf16
    const u16* __restrict__ wpA,    // packed weights (perm space)
    const float* __restrict__ maskp,
    const u16* __restrict__ zeropad,
    const int* __restrict__ kp,     // {Kc16, nq, K, 0, qlist[8]}
    u16* __restrict__ outb)         // chunk-major [8][NHW][32] bf16
{
    __shared__ u16 lds[3][7680];    // ring-3 x 15360 B

    const int tid  = threadIdx.x;
    const int wave = tid >> 6, lane = tid & 63;
    const int l15  = lane & 15, lq = lane >> 4;
    const int wave_co = wave >> 1, wave_px = wave & 1;
    const int xcd = blockIdx.x & 7, r_ = blockIdx.x >> 3;
    const int yco = r_ & 1;
    const int sb  = xcd * 112 + (r_ >> 1);
    const int n = sb / 28, hb = sb % 28;
    const int h0 = hb * 2;
    const int cog_base = yco * 8 + wave_co * 4;
    const size_t abase0 = (size_t)cog_base * 512 + (size_t)(l15 * 32 + lq * 8);

    const int Kc = kp[0];
    const int nq = kp[1];
    int nf = (Kc >> 4) - cog_base;
    nf = nf < 0 ? 0 : (nf > 4 ? 4 : nf);

    f32x4 acc[4][4];
#pragma unroll
    for (int i = 0; i < 4; ++i)
#pragma unroll
        for (int j = 0; j < 4; ++j) acc[i][j] = (f32x4){0.f, 0.f, 0.f, 0.f};

    // stage chunk q (32 ci) into ring buffer b: 232 pixel-rows (4 halo rows x
    // 58 slots) x 4 octs = 928 lane-slots; 15 wave-instrs (waves 0-2: 4 ops,
    // wave 3: 3 ops); 32-slot tail -> zeropad (zeroes LDS slack rows).
    auto stage = [&](int q, int b) {
        const u16* plane = xb + (size_t)q * PLANE_;
        for (int is = wave; is < 15; is += 4) {
            int L = is * 64 + lane;            // 0..959
            int pixel = L >> 2, so = L & 3;    // LDS layout index
            int rr = pixel / 58, slot = pixel - rr * 58;
            int oct = so ^ ((slot >> 1) & 3);  // global ci-oct for this slot
            int row = h0 - 1 + rr, col = slot - 1;
            bool ok = pixel < 232 &&
                      (unsigned)row < (unsigned)H_ && (unsigned)col < (unsigned)W_;
            const u16* gp = ok
                ? plane + ((size_t)(n * H_ + row) * W_ + col) * 32 + oct * 8
                : zeropad + oct * 8;
            gload_lds16(gp, &lds[b][is * 512]);
        }
    };

    short8 afq[3][4];
    auto loadA = [&](int rs_, int q, short8 dst[4]) {
        const size_t bb = (size_t)rs_ * 65536 + (size_t)q * 8192 + abase0;
#pragma unroll
        for (int fm = 0; fm < 4; ++fm)
            if (fm < nf) dst[fm] = *(const short8*)(wpA + bb + (size_t)fm * 512);
    };

    if (nq > 0) {
        const int q0 = kp[4];
        stage(q0, 0);
        __builtin_amdgcn_sched_barrier(0);
        loadA(0, q0, afq[0]);
        loadA(1, q0, afq[1]);
        __builtin_amdgcn_sched_barrier(0);
        if (nq > 1) {
            stage(kp[5], 1);
            __builtin_amdgcn_sched_barrier(0);
            asm volatile("s_waitcnt vmcnt(3)" ::: "memory");
        } else {
            asm volatile("s_waitcnt vmcnt(0)" ::: "memory");
        }
        __builtin_amdgcn_sched_barrier(0);
        __builtin_amdgcn_s_barrier();
        __builtin_amdgcn_sched_barrier(0);

        for (int t = 0; t < nq; ++t) {
            const int q  = kp[4 + t];
            const int qn = kp[4 + (t + 1 < nq ? t + 1 : t)];
            const u16* Lb = &lds[t % 3][0];
#pragma unroll
            for (int rs = 0; rs < 9; ++rs) {
                // A-frag prefetch 2 steps deep (wraps into next chunk's rs0/1;
                // for the last chunk it re-reads valid memory, values unused)
                if (rs < 7) loadA(rs + 2, q, afq[(rs + 2) % 3]);
                else        loadA(rs - 7, qn, afq[(rs + 2) % 3]);
                const int r = rs / 3, s = rs - (rs / 3) * 3;
                short8 bf[4];
#pragma unroll
                for (int fn = 0; fn < 4; ++fn) {
                    int slot = fn * 16 + l15 + s;
                    int pixel = (wave_px + r) * 58 + slot;
                    int so = lq ^ ((slot >> 1) & 3);
                    bf[fn] = *(const short8*)(Lb + pixel * 32 + so * 8);
                }
#pragma unroll
                for (int fm = 0; fm < 4; ++fm)
                    if (fm < nf) {
#pragma unroll
                        for (int fn = 0; fn < 4; ++fn)
                            acc[fm][fn] = __builtin_amdgcn_mfma_f32_16x16x32_bf16(
                                afq[rs % 3][fm], bf[fn], acc[fm][fn], 0, 0, 0);
                    }
            }
            __builtin_amdgcn_sched_barrier(0);
            if (t + 2 < nq) stage(kp[6 + t], (t + 2) % 3);
            __builtin_amdgcn_sched_barrier(0);
            if (t + 1 < nq) {
                // own stage(t+1) done (it has >=3 own ops after it); stage(t+2)
                // (the <=4 newest) may remain in flight across the barrier.
                if (t + 2 < nq) asm volatile("s_waitcnt vmcnt(3)" ::: "memory");
                else            asm volatile("s_waitcnt vmcnt(0)" ::: "memory");
                __builtin_amdgcn_sched_barrier(0);
                __builtin_amdgcn_s_barrier();
                __builtin_amdgcn_sched_barrier(0);
            }
        }
    }

    // epilogue: C/D col=lane&15 (pixel), row=lq*4+reg (co, perm space).
    // maskp folded -> dead/masked channels get exact zeros (stats need them).
    const int row = h0 + wave_px;
#pragma unroll
    for (int fn = 0; fn < 4; ++fn) {
        int px = fn * 16 + l15;
        if (px < W_) {
#pragma unroll
            for (int fm = 0; fm < 4; ++fm) {
                int co_b = cog_base * 16 + fm * 16 + lq * 4;
                const f32x4 mk = *(const f32x4*)(maskp + co_b);
                size_t base = (size_t)(co_b >> 5) * PLANE_
                            + ((size_t)(n * H_ + row) * W_ + px) * 32 + (co_b & 31);
                ushort4 o;
                o.x = f2b(acc[fm][fn][0] * mk[0]);
                o.y = f2b(acc[fm][fn][1] * mk[1]);
                o.z = f2b(acc[fm][fn][2] * mk[2]);
                o.w = f2b(acc[fm][fn][3] * mk[3]);
                *(ushort4*)(outb + base) = o;
            }
        }
    }
}

// ---------------------------------------------------------------------------
// zero stats accumulators + scale/shift + zeropad scratch (12 KB). grid 12.
extern "C" __global__ void zero_accum_kernel(float* __restrict__ p) {
    p[blockIdx.x * 256 + threadIdx.x] = 0.f;
}

// Per-channel sum/sumsq over chunk-major bf16 via block partials + atomics.
// grid 392. Channel for lane l, elem j is 8l+j (positional, perm space).
extern "C" __global__ __launch_bounds__(256) void stats_nhwc_kernel(
    const u16* __restrict__ hb, float* __restrict__ gsum, float* __restrict__ gsq)
{
    __shared__ float s_s[8 * 256];
    __shared__ float s_q[8 * 256];
    const int g = threadIdx.x >> 5, l = threadIdx.x & 31;
    const size_t pbase_off = (size_t)(l >> 2) * PLANE_ + (l & 3) * 8;
    float s[8], q[8];
#pragma unroll
    for (int j = 0; j < 8; ++j) { s[j] = 0.f; q[j] = 0.f; }
    const int pbase = blockIdx.x * 256;
    for (int t = 0; t < 32; ++t) {
        int p = pbase + g + t * 8;
        short8 v = *(const short8*)(hb + pbase_off + (size_t)p * 32);
#pragma unroll
        for (int j = 0; j < 8; ++j) {
            float f = b2f((u16)v[j]);
            s[j] += f; q[j] += f * f;
        }
    }
#pragma unroll
    for (int j = 0; j < 8; ++j) {
        s_s[g * 256 + l * 8 + j] = s[j];
        s_q[g * 256 + l * 8 + j] = q[j];
    }
    __syncthreads();
    const int c = threadIdx.x;
    float S = 0.f, Q = 0.f;
#pragma unroll
    for (int g2 = 0; g2 < 8; ++g2) { S += s_s[g2 * 256 + c]; Q += s_q[g2 * 256 + c]; }
    atomicAdd(&gsum[c], S);
    atomicAdd(&gsq[c], Q);
}

// scale/shift from accumulated stats (perm space); gamma/beta gathered. 1x256.
extern "C" __global__ void finalize_bn_kernel(
    const float* __restrict__ gsum, const float* __restrict__ gsq,
    const float* __restrict__ gamma, const float* __restrict__ beta,
    const int* __restrict__ perm,
    float* __restrict__ scale, float* __restrict__ shift)
{
    const int c = threadIdx.x;
    const int co = perm[c];
    const float inv_n = 1.f / (float)NHW_;
    float mean = gsum[c] * inv_n;
    float var  = gsq[c] * inv_n - mean * mean;
    var = fmaxf(var, 0.f);
    float inv = rsqrtf(var + 1e-5f);
    float sc = gamma[co] * inv;
    scale[c] = sc;
    shift[c] = beta[co] - mean * sc;
}

// In-place BN+ReLU on chunk-major bf16 (perm space). grid 12544.
extern "C" __global__ __launch_bounds__(256) void bn_relu_nhwc_kernel(
    u16* __restrict__ hb, const float* __restrict__ scale, const float* __restrict__ shift)
{
    size_t idx = ((size_t)blockIdx.x * 256 + threadIdx.x) * 8;
    int c0 = (int)(blockIdx.x / 1568) * 32 + (int)(idx & 31);
    short8 v = *(short8*)(hb + idx);
    short8 o;
#pragma unroll
    for (int j = 0; j < 8; ++j) {
        int c = c0 + j;
        float f = b2f((u16)v[j]) * scale[c] + shift[c];
        o[j] = (short)f2b(fmaxf(f, 0.f));
    }
    *(short8*)(hb + idx) = o;
}

// out = relu(bn2(h2) + x): chunk-major bf16 (perm2 space) -> NCHW fp32.
// grid (n,h); channel map perm2: perm-space c -> original channel.
extern "C" __global__ __launch_bounds__(256) void bn_add_relu_out_kernel(
    const u16* __restrict__ h2b, const float* __restrict__ x,
    const float* __restrict__ scale, const float* __restrict__ shift,
    const int* __restrict__ perm,
    float* __restrict__ out)
{
    __shared__ float t[64 * 57];
    const int nh = blockIdx.x, n = nh / H_, h = nh % H_;
    const size_t pix0 = (size_t)(n * H_ + h) * W_;
    for (int cb = 0; cb < 4; ++cb) {
        __syncthreads();
        for (int it = threadIdx.x; it < 448; it += 256) {      // 56 px * 8 octs
            int w = it >> 3, oc = it & 7;
            size_t addr = (size_t)(cb * 2 + (oc >> 2)) * PLANE_
                        + (pix0 + w) * 32 + (oc & 3) * 8;
            short8 v = *(const short8*)(h2b + addr);
#pragma unroll
            for (int j = 0; j < 8; ++j) t[(oc * 8 + j) * 57 + w] = b2f((u16)v[j]);
        }
        __syncthreads();
        for (int it = threadIdx.x; it < 64 * 56; it += 256) {
            int cl = it / 56, w = it % 56;
            int c = cb * 64 + cl;              // perm space
            int co = perm[c];                  // original channel
            size_t oidx = ((size_t)(n * C_ + co) * H_ + h) * W_ + w;
            float v = t[cl * 57 + w] * scale[c] + shift[c] + x[oidx];
            out[oidx] = fmaxf(v, 0.f);
        }
    }
}

// ---------------------------------------------------------------------------
extern "C" void kernel_launch(void* const* d_in, const int* in_sizes, int n_in,
                              void* d_out, int out_size, void* d_ws, size_t ws_size,
                              hipStream_t stream) {
    const float* x      = (const float*)d_in[0];
    const float* W1     = (const float*)d_in[1];
    const float* W2     = (const float*)d_in[2];
    const float* gamma1 = (const float*)d_in[3];
    const float* beta1  = (const float*)d_in[4];
    const float* gamma2 = (const float*)d_in[5];
    const float* beta2  = (const float*)d_in[6];
    const float* mask1  = (const float*)d_in[7];
    const float* mask2  = (const float*)d_in[8];
    float* out = (float*)d_out;

    // ws layout (NO overlaps — round-5 bug was zeropad aliasing scale/shift):
    // [0,4K)     stats accumulators (gsum1,gsq1,gsum2,gsq2)
    // [4K,8K)    scale1,shift1,scale2,shift2
    // [8K,12K)   zeropad scratch (zeroed every launch, read-only thereafter)
    // [12K,17K)  perm1,perm2,maskp1,maskp2,id256 (1 KB each)
    // [17K,+128) kpar1,kpar2 (16 ints each)
    // [20K,..)   Wp1 | Wp2 | xb (reused as h2b)
    char* ws = (char*)d_ws;
    float* gsum1  = (float*)ws;
    float* gsq1   = gsum1 + 256;
    float* gsum2  = gsq1 + 256;
    float* gsq2   = gsum2 + 256;
    float* scale1 = gsq2 + 256;
    float* shift1 = scale1 + 256;
    float* scale2 = shift1 + 256;
    float* shift2 = scale2 + 256;
    u16*   zeropad = (u16*)(ws + 8192);
    int*   perm1  = (int*)(ws + 12288);
    int*   perm2  = (int*)(ws + 13312);
    float* maskp1 = (float*)(ws + 14336);
    float* maskp2 = (float*)(ws + 15360);
    int*   id256  = (int*)(ws + 16384);
    int*   kpar1  = (int*)(ws + 17408);
    int*   kpar2  = (int*)(ws + 17472);
    u16* Wp1 = (u16*)(ws + 20480);
    u16* Wp2 = Wp1 + 9 * 256 * 256;
    u16* xb  = Wp2 + 9 * 256 * 256;
    u16* h2b = xb;                          // xb dead after conv1
    u16* h1b = (u16*)d_out;                 // bf16 scratch inside 102.8 MB output

    zero_accum_kernel<<<dim3(12), dim3(256), 0, stream>>>(gsum1);  // stats+scales+zeropad
    mask_scan_kernel<<<dim3(1), dim3(256), 0, stream>>>(mask1, perm1, maskp1, kpar1, id256);
    mask_scan_kernel<<<dim3(1), dim3(256), 0, stream>>>(mask2, perm2, maskp2, kpar2, id256);
    cvt_x_kernel<<<dim3(N_ * H_), dim3(256), 0, stream>>>(x, xb);
    pack_w_kernel<<<dim3(2304), dim3(256), 0, stream>>>(W1, perm1, id256, Wp1);
    pack_w_kernel<<<dim3(2304), dim3(256), 0, stream>>>(W2, perm2, perm1, Wp2);

    dim3 cgrid(N_ * 56);   // 1792 1-D (pair-local XCD swizzle in-kernel)
    BasicBlock_4355096838467_kernel<<<cgrid, dim3(256), 0, stream>>>(
        xb, Wp1, maskp1, zeropad, kpar1, h1b);
    stats_nhwc_kernel<<<dim3(392), dim3(256), 0, stream>>>(h1b, gsum1, gsq1);
    finalize_bn_kernel<<<dim3(1), dim3(256), 0, stream>>>(
        gsum1, gsq1, gamma1, beta1, perm1, scale1, shift1);
    chunk_sel_kernel<<<dim3(1), dim3(256), 0, stream>>>(shift1, kpar1, kpar2);
    bn_relu_nhwc_kernel<<<dim3(12544), dim3(256), 0, stream>>>(h1b, scale1, shift1);

    BasicBlock_4355096838467_kernel<<<cgrid, dim3(256), 0, stream>>>(
        h1b, Wp2, maskp2, zeropad, kpar2, h2b);
    stats_nhwc_kernel<<<dim3(392), dim3(256), 0, stream>>>(h2b, gsum2, gsq2);
    finalize_bn_kernel<<<dim3(1), dim3(256), 0, stream>>>(
        gsum2, gsq2, gamma2, beta2, perm2, scale2, shift2);
    bn_add_relu_out_kernel<<<dim3(N_ * H_), dim3(256), 0, stream>>>(
        h2b, x, scale2, shift2, perm2, out);
}

// Round 4
// 590.074 us; speedup vs baseline: 1.5775x; 1.0146x over previous
//
#include <hip/hip_runtime.h>

// BasicBlock: N=32, C=256, H=W=56, two 3x3 convs (stride 1, pad 1), channel
// masks, training-mode BN, residual+ReLU. fp32 I/O; convs on bf16 MFMA.
//
// Activations: chunk-major bf16 [8 planes][N*H*W][32 ci] (round-1 lesson:
// full 128-B lines per staging chunk). Channels PERMUTED so mask-surviving
// channels come first: conv blocks whose whole 128-co half is dead EXIT
// IMMEDIATELY (round-4: round-3 left them staging+ds_reading for zero MFMA
// -> half the LDS bandwidth wasted); their unwritten output planes are
// reconstructed downstream (stats skip = true zeros; bn_relu writes
// relu(shift); bn_add_relu reads 0). conv2 also skips provably-zero
// ci-chunks (device-built qlist). All mask logic device-computed.
#define N_   32
#define C_   256
#define H_   56
#define W_   56
#define HW_  (H_ * W_)        // 3136
#define NHW_ (N_ * HW_)       // 100352
#define PLANE_ ((size_t)NHW_ * 32)   // u16 elems per 32-ci plane

typedef unsigned short u16;
typedef __attribute__((ext_vector_type(8))) short short8;   // 8 bf16
typedef __attribute__((ext_vector_type(4))) float f32x4;

__device__ __forceinline__ float b2f(u16 u) {
    union { unsigned int i; float f; } v; v.i = ((unsigned int)u) << 16; return v.f;
}
__device__ __forceinline__ u16 f2b(float f) {
    union { float f; unsigned int i; } v; v.f = f;
    unsigned int r = v.i + 0x7fffu + ((v.i >> 16) & 1u);   // RNE
    return (u16)(r >> 16);
}

typedef const __attribute__((address_space(1))) unsigned int* as1_u32p;
typedef __attribute__((address_space(3))) unsigned int* as3_u32p;
__device__ __forceinline__ void gload_lds16(const u16* g, u16* l) {
    __builtin_amdgcn_global_load_lds((as1_u32p)g, (as3_u32p)l, 16, 0, 0);
}

// ---------------------------------------------------------------------------
// x (fp32 NCHW) -> xb (bf16 chunk-major). Block = (n,h); LDS transpose.
extern "C" __global__ __launch_bounds__(256) void cvt_x_kernel(
    const float* __restrict__ x, u16* __restrict__ xb)
{
    __shared__ float t[64 * 57];
    const int nh = blockIdx.x, n = nh / H_, h = nh % H_;
    const size_t pix0 = (size_t)(n * H_ + h) * W_;
    for (int cb = 0; cb < 4; ++cb) {
        __syncthreads();
        for (int idx = threadIdx.x; idx < 64 * 56; idx += 256) {
            int cc = idx / 56, w = idx % 56;
            t[cc * 57 + w] = x[(((size_t)(n * C_ + cb * 64 + cc)) * H_ + h) * W_ + w];
        }
        __syncthreads();
        for (int idx = threadIdx.x; idx < 56 * 64; idx += 256) {
            int w = idx >> 6, cc = idx & 63;
            int plane = cb * 2 + (cc >> 5);
            xb[(size_t)plane * PLANE_ + (pix0 + w) * 32 + (cc & 31)] = f2b(t[cc * 57 + w]);
        }
    }
}

// ---------------------------------------------------------------------------
// Both mask scans in one launch (grid 2). perm = survivors first, maskp =
// gathered mask, kpar = { ceil16(K), nq=8, K, 0, qlist 0..7 }. Block 0 also
// writes id256 (identity perm for conv1's ci side).
extern "C" __global__ void mask_scan_kernel(
    const float* __restrict__ m1, const float* __restrict__ m2,
    int* __restrict__ p1, int* __restrict__ p2,
    float* __restrict__ mp1, float* __restrict__ mp2,
    int* __restrict__ k1, int* __restrict__ k2, int* __restrict__ id256)
{
    const float* mask  = blockIdx.x ? m2 : m1;
    int*   perm  = blockIdx.x ? p2 : p1;
    float* maskp = blockIdx.x ? mp2 : mp1;
    int*   kpar  = blockIdx.x ? k2 : k1;
    __shared__ float m[256];
    const int c = threadIdx.x;
    m[c] = mask[c];
    if (blockIdx.x == 0) id256[c] = c;
    __syncthreads();
    int pre = 0, tot = 0;
    for (int i = 0; i < 256; ++i) {
        int nz = (m[i] != 0.f) ? 1 : 0;
        if (i < c) pre += nz;
        tot += nz;
    }
    const int nz = (m[c] != 0.f) ? 1 : 0;
    const int pos = nz ? pre : tot + (c - pre);
    perm[pos] = c;
    maskp[pos] = m[c];
    if (c == 0) {
        kpar[0] = ((tot + 15) >> 4) << 4;   // Kc16: co-tiles above this are dead
        kpar[1] = 8;                        // nq (default: all chunks)
        kpar[2] = tot;                      // raw survivor count K
        kpar[3] = 0;
    }
    if (c < 8) kpar[4 + c] = c;             // identity qlist
}

// conv2 ci-chunk selection: chunk q of h1 (perm1 space) is skippable iff all
// its channels are masked-dead (exact 0 pre-BN) AND relu(shift1)==0 (then
// post-BN-ReLU value is exactly 0).
extern "C" __global__ void chunk_sel_kernel(
    const float* __restrict__ shift, const int* __restrict__ kparK,
    int* __restrict__ kpar)
{
    __shared__ int act[8];
    const int c = threadIdx.x;
    if (c < 8) act[c] = 0;
    __syncthreads();
    const int K = kparK[2];
    const bool a = (c < K) || (shift[c] > 0.f);
    if (a) atomicOr(&act[c >> 5], 1);
    __syncthreads();
    if (c == 0) {
        int nq = 0;
        for (int q = 0; q < 8; ++q) if (act[q]) kpar[4 + nq++] = q;
        kpar[1] = nq;
    }
}

// ---------------------------------------------------------------------------
// W [co][ci][3][3] fp32 -> wpA [rs][cih 8][cog 16][l15 16][lq 4][j 8] bf16,
// gathered through operm (output-channel perm) and iperm (input-channel perm).
extern "C" __global__ __launch_bounds__(256) void pack_w_kernel(
    const float* __restrict__ w, const int* __restrict__ operm,
    const int* __restrict__ iperm, u16* __restrict__ wp)
{
    int o = blockIdx.x * 256 + threadIdx.x;      // grid 2304 -> 589824
    int j = o & 7, lq = (o >> 3) & 3, l15 = (o >> 5) & 15;
    int cog = (o >> 9) & 15, cih = (o >> 13) & 7, rs = o >> 16;
    int co = operm[cog * 16 + l15];
    int ci = iperm[cih * 32 + lq * 8 + j];
    wp[o] = f2b(w[((size_t)co * C_ + ci) * 9 + rs]);
}

// ---------------------------------------------------------------------------
// Implicit-GEMM 3x3 conv on MFMA. 1-D grid 1792: id -> (xcd=id&7, r=id>>3),
// y = r&1 (co half), sb = xcd*112 + (r>>1) -> the two co-halves of one pixel
// tile land on the SAME XCD, adjacent in dispatch -> staging L2 reuse.
// 4 waves: wave>>1 = co quarter-within-half, wave&1 = output row.
// Wave tile 64co x 64px = 4x4 grid of mfma_f32_16x16x32_bf16.
//
// Ring-3 LDS + raw s_barrier + counted vmcnt so the stage queue never drains
// (round-2 lesson: __syncthreads' vmcnt(0) drain made the conv latency-bound).
// Round-4: blocks whose whole co-half is dead (Kc16 <= yco*128) EXIT before
// touching anything (round-3 lesson: they consumed half the LDS read BW and
// halved MfmaUtil); waves with nf==0 in live blocks skip B-reads + MFMA;
// s_setprio(1) wraps the MFMA cluster (T5 -- phase-split schedule exists).
//
// LDS rows = 4 octs of 16 B, XOR-swizzled by ((slot>>1)&3) (conflict-free,
// verified: SQ_LDS_BANK_CONFLICT == 0); swizzle baked into the GLOBAL address
// (LDS dest of global_load_lds is wave-uniform base+lane*16).
// Halo/OOB lanes read a DEDICATED zeroed scratch (aliasing bug history).
extern "C" __global__ __launch_bounds__(256, 3) void BasicBlock_4355096838467_kernel(
    const u16* __restrict__ xb,     // chunk-major [8][NHW][32] bf16
    const u16* __restrict__ wpA,    // packed weights (perm space)
    const float* __restrict__ maskp,
    const u16* __restrict__ zeropad,
    const int* __restrict__ kp,     // {Kc16, nq, K, 0, qlist[8]}
    u16* __restrict__ outb)         // chunk-major [8][NHW][32] bf16
{
    __shared__ u16 lds[3][7680];    // ring-3 x 15360 B

    const int tid  = threadIdx.x;
    const int wave = tid >> 6, lane = tid & 63;
    const int l15  = lane & 15, lq = lane >> 4;
    const int wave_co = wave >> 1, wave_px = wave & 1;
    const int xcd = blockIdx.x & 7, r_ = blockIdx.x >> 3;
    const int yco = r_ & 1;

    const int Kc = kp[0];
    if (Kc <= yco * 128) return;    // whole co-half dead: downstream kernels
                                    // reconstruct the unwritten planes
    const int nq = kp[1];

    const int sb  = xcd * 112 + (r_ >> 1);
    const int n = sb / 28, hb = sb % 28;
    const int h0 = hb * 2;
    const int cog_base = yco * 8 + wave_co * 4;
    const size_t abase0 = (size_t)cog_base * 512 + (size_t)(l15 * 32 + lq * 8);

    int nf = (Kc >> 4) - cog_base;
    nf = nf < 0 ? 0 : (nf > 4 ? 4 : nf);

    f32x4 acc[4][4];
#pragma unroll
    for (int i = 0; i < 4; ++i)
#pragma unroll
        for (int j = 0; j < 4; ++j) acc[i][j] = (f32x4){0.f, 0.f, 0.f, 0.f};

    // stage chunk q (32 ci) into ring buffer b: 232 pixel-rows (4 halo rows x
    // 58 slots) x 4 octs = 928 lane-slots; 15 wave-instrs (waves 0-2: 4 ops,
    // wave 3: 3 ops); 32-slot tail -> zeropad (zeroes LDS slack rows).
    auto stage = [&](int q, int b) {
        const u16* plane = xb + (size_t)q * PLANE_;
        for (int is = wave; is < 15; is += 4) {
            int L = is * 64 + lane;            // 0..959
            int pixel = L >> 2, so = L & 3;    // LDS layout index
            int rr = pixel / 58, slot = pixel - rr * 58;
            int oct = so ^ ((slot >> 1) & 3);  // global ci-oct for this slot
            int row = h0 - 1 + rr, col = slot - 1;
            bool ok = pixel < 232 &&
                      (unsigned)row < (unsigned)H_ && (unsigned)col < (unsigned)W_;
            const u16* gp = ok
                ? plane + ((size_t)(n * H_ + row) * W_ + col) * 32 + oct * 8
                : zeropad + oct * 8;
            gload_lds16(gp, &lds[b][is * 512]);
        }
    };

    short8 afq[3][4];
    auto loadA = [&](int rs_, int q, short8 dst[4]) {
        const size_t bb = (size_t)rs_ * 65536 + (size_t)q * 8192 + abase0;
#pragma unroll
        for (int fm = 0; fm < 4; ++fm)
            if (fm < nf) dst[fm] = *(const short8*)(wpA + bb + (size_t)fm * 512);
    };

    if (nq > 0) {
        const int q0 = kp[4];
        stage(q0, 0);
        __builtin_amdgcn_sched_barrier(0);
        loadA(0, q0, afq[0]);
        loadA(1, q0, afq[1]);
        __builtin_amdgcn_sched_barrier(0);
        if (nq > 1) {
            stage(kp[5], 1);
            __builtin_amdgcn_sched_barrier(0);
            asm volatile("s_waitcnt vmcnt(3)" ::: "memory");
        } else {
            asm volatile("s_waitcnt vmcnt(0)" ::: "memory");
        }
        __builtin_amdgcn_sched_barrier(0);
        __builtin_amdgcn_s_barrier();
        __builtin_amdgcn_sched_barrier(0);

        for (int t = 0; t < nq; ++t) {
            const int q  = kp[4 + t];
            const int qn = kp[4 + (t + 1 < nq ? t + 1 : t)];
            const u16* Lb = &lds[t % 3][0];
            if (nf > 0) {
#pragma unroll
                for (int rs = 0; rs < 9; ++rs) {
                    // A-frag prefetch 2 deep (wraps into next chunk's rs0/1;
                    // for the last chunk it re-reads valid memory, unused)
                    if (rs < 7) loadA(rs + 2, q, afq[(rs + 2) % 3]);
                    else        loadA(rs - 7, qn, afq[(rs + 2) % 3]);
                    const int r = rs / 3, s = rs - (rs / 3) * 3;
                    short8 bf[4];
#pragma unroll
                    for (int fn = 0; fn < 4; ++fn) {
                        int slot = fn * 16 + l15 + s;
                        int pixel = (wave_px + r) * 58 + slot;
                        int so = lq ^ ((slot >> 1) & 3);
                        bf[fn] = *(const short8*)(Lb + pixel * 32 + so * 8);
                    }
                    __builtin_amdgcn_s_setprio(1);
#pragma unroll
                    for (int fm = 0; fm < 4; ++fm)
                        if (fm < nf) {
#pragma unroll
                            for (int fn = 0; fn < 4; ++fn)
                                acc[fm][fn] = __builtin_amdgcn_mfma_f32_16x16x32_bf16(
                                    afq[rs % 3][fm], bf[fn], acc[fm][fn], 0, 0, 0);
                        }
                    __builtin_amdgcn_s_setprio(0);
                }
            }
            __builtin_amdgcn_sched_barrier(0);
            if (t + 2 < nq) stage(kp[6 + t], (t + 2) % 3);
            __builtin_amdgcn_sched_barrier(0);
            if (t + 1 < nq) {
                // own stage(t+1) done; stage(t+2) (the <=4 newest) may remain
                // in flight across the barrier.
                if (t + 2 < nq) asm volatile("s_waitcnt vmcnt(3)" ::: "memory");
                else            asm volatile("s_waitcnt vmcnt(0)" ::: "memory");
                __builtin_amdgcn_sched_barrier(0);
                __builtin_amdgcn_s_barrier();
                __builtin_amdgcn_sched_barrier(0);
            }
        }
    }

    // epilogue: C/D col=lane&15 (pixel), row=lq*4+reg (co, perm space).
    // maskp folded -> dead/masked channels inside live blocks get exact zeros.
    const int row = h0 + wave_px;
#pragma unroll
    for (int fn = 0; fn < 4; ++fn) {
        int px = fn * 16 + l15;
        if (px < W_) {
#pragma unroll
            for (int fm = 0; fm < 4; ++fm) {
                int co_b = cog_base * 16 + fm * 16 + lq * 4;
                const f32x4 mk = *(const f32x4*)(maskp + co_b);
                size_t base = (size_t)(co_b >> 5) * PLANE_
                            + ((size_t)(n * H_ + row) * W_ + px) * 32 + (co_b & 31);
                ushort4 o;
                o.x = f2b(acc[fm][fn][0] * mk[0]);
                o.y = f2b(acc[fm][fn][1] * mk[1]);
                o.z = f2b(acc[fm][fn][2] * mk[2]);
                o.w = f2b(acc[fm][fn][3] * mk[3]);
                *(ushort4*)(outb + base) = o;
            }
        }
    }
}

// ---------------------------------------------------------------------------
// zero stats accumulators + scale/shift + zeropad scratch (12 KB). grid 12.
extern "C" __global__ void zero_accum_kernel(float* __restrict__ p) {
    p[blockIdx.x * 256 + threadIdx.x] = 0.f;
}

// Per-channel sum/sumsq over chunk-major bf16 via block partials + atomics.
// grid 392. Channel for lane l, elem j is 8l+j (positional, perm space).
// Lanes whose plane-group was never written (K <= 128*(l>>4)) skip: the
// zeroed accumulators already hold the true all-zero-channel stats.
extern "C" __global__ __launch_bounds__(256) void stats_nhwc_kernel(
    const u16* __restrict__ hb, const int* __restrict__ kp,
    float* __restrict__ gsum, float* __restrict__ gsq)
{
    __shared__ float s_s[8 * 256];
    __shared__ float s_q[8 * 256];
    const int g = threadIdx.x >> 5, l = threadIdx.x & 31;
    const size_t pbase_off = (size_t)(l >> 2) * PLANE_ + (l & 3) * 8;
    const bool live = kp[2] > 128 * (l >> 4);
    float s[8], q[8];
#pragma unroll
    for (int j = 0; j < 8; ++j) { s[j] = 0.f; q[j] = 0.f; }
    const int pbase = blockIdx.x * 256;
    if (live) {
        for (int t = 0; t < 32; ++t) {
            int p = pbase + g + t * 8;
            short8 v = *(const short8*)(hb + pbase_off + (size_t)p * 32);
#pragma unroll
            for (int j = 0; j < 8; ++j) {
                float f = b2f((u16)v[j]);
                s[j] += f; q[j] += f * f;
            }
        }
    }
#pragma unroll
    for (int j = 0; j < 8; ++j) {
        s_s[g * 256 + l * 8 + j] = s[j];
        s_q[g * 256 + l * 8 + j] = q[j];
    }
    __syncthreads();
    const int c = threadIdx.x;
    float S = 0.f, Q = 0.f;
#pragma unroll
    for (int g2 = 0; g2 < 8; ++g2) { S += s_s[g2 * 256 + c]; Q += s_q[g2 * 256 + c]; }
    atomicAdd(&gsum[c], S);
    atomicAdd(&gsq[c], Q);
}

// scale/shift from accumulated stats (perm space); gamma/beta gathered. 1x256.
extern "C" __global__ void finalize_bn_kernel(
    const float* __restrict__ gsum, const float* __restrict__ gsq,
    const float* __restrict__ gamma, const float* __restrict__ beta,
    const int* __restrict__ perm,
    float* __restrict__ scale, float* __restrict__ shift)
{
    const int c = threadIdx.x;
    const int co = perm[c];
    const float inv_n = 1.f / (float)NHW_;
    float mean = gsum[c] * inv_n;
    float var  = gsq[c] * inv_n - mean * mean;
    var = fmaxf(var, 0.f);
    float inv = rsqrtf(var + 1e-5f);
    float sc = gamma[co] * inv;
    scale[c] = sc;
    shift[c] = beta[co] - mean * sc;
}

// In-place BN+ReLU on chunk-major bf16 (perm space). grid 12544.
// Planes never written by conv (K <= 128*(plane>>2)) get relu(shift[c])
// written WITHOUT reading (true channel value is exactly 0) -- this also
// materializes valid data for tail chunks conv2's qlist keeps.
extern "C" __global__ __launch_bounds__(256) void bn_relu_nhwc_kernel(
    u16* __restrict__ hb, const float* __restrict__ scale,
    const float* __restrict__ shift, const int* __restrict__ kp)
{
    size_t idx = ((size_t)blockIdx.x * 256 + threadIdx.x) * 8;
    const int plane = (int)(blockIdx.x / 1568);
    const int c0 = plane * 32 + (int)(idx & 31);
    short8 o;
    if (kp[2] > 128 * (plane >> 2)) {
        short8 v = *(short8*)(hb + idx);
#pragma unroll
        for (int j = 0; j < 8; ++j) {
            float f = b2f((u16)v[j]) * scale[c0 + j] + shift[c0 + j];
            o[j] = (short)f2b(fmaxf(f, 0.f));
        }
    } else {
#pragma unroll
        for (int j = 0; j < 8; ++j)
            o[j] = (short)f2b(fmaxf(shift[c0 + j], 0.f));
    }
    *(short8*)(hb + idx) = o;
}

// out = relu(bn2(h2) + x): chunk-major bf16 (perm2 space) -> NCHW fp32.
// grid (n,h). Unwritten h2 planes (K2 <= 128*(plane>>2)) read as exact 0.
extern "C" __global__ __launch_bounds__(256) void bn_add_relu_out_kernel(
    const u16* __restrict__ h2b, const float* __restrict__ x,
    const float* __restrict__ scale, const float* __restrict__ shift,
    const int* __restrict__ perm, const int* __restrict__ kp,
    float* __restrict__ out)
{
    __shared__ float t[64 * 57];
    const int nh = blockIdx.x, n = nh / H_, h = nh % H_;
    const size_t pix0 = (size_t)(n * H_ + h) * W_;
    const int K2 = kp[2];
    for (int cb = 0; cb < 4; ++cb) {
        __syncthreads();
        for (int it = threadIdx.x; it < 448; it += 256) {      // 56 px * 8 octs
            int w = it >> 3, oc = it & 7;
            int plane = cb * 2 + (oc >> 2);
            short8 v = {0, 0, 0, 0, 0, 0, 0, 0};
            if (K2 > 128 * (plane >> 2)) {
                size_t addr = (size_t)plane * PLANE_ + (pix0 + w) * 32 + (oc & 3) * 8;
                v = *(const short8*)(h2b + addr);
            }
#pragma unroll
            for (int j = 0; j < 8; ++j) t[(oc * 8 + j) * 57 + w] = b2f((u16)v[j]);
        }
        __syncthreads();
        for (int it = threadIdx.x; it < 64 * 56; it += 256) {
            int cl = it / 56, w = it % 56;
            int c = cb * 64 + cl;              // perm space
            int co = perm[c];                  // original channel
            size_t oidx = ((size_t)(n * C_ + co) * H_ + h) * W_ + w;
            float v = t[cl * 57 + w] * scale[c] + shift[c] + x[oidx];
            out[oidx] = fmaxf(v, 0.f);
        }
    }
}

// ---------------------------------------------------------------------------
extern "C" void kernel_launch(void* const* d_in, const int* in_sizes, int n_in,
                              void* d_out, int out_size, void* d_ws, size_t ws_size,
                              hipStream_t stream) {
    const float* x      = (const float*)d_in[0];
    const float* W1     = (const float*)d_in[1];
    const float* W2     = (const float*)d_in[2];
    const float* gamma1 = (const float*)d_in[3];
    const float* beta1  = (const float*)d_in[4];
    const float* gamma2 = (const float*)d_in[5];
    const float* beta2  = (const float*)d_in[6];
    const float* mask1  = (const float*)d_in[7];
    const float* mask2  = (const float*)d_in[8];
    float* out = (float*)d_out;

    // ws layout (NO overlaps — round-5 bug was zeropad aliasing scale/shift):
    // [0,4K)     stats accumulators (gsum1,gsq1,gsum2,gsq2)
    // [4K,8K)    scale1,shift1,scale2,shift2
    // [8K,12K)   zeropad scratch (zeroed every launch, read-only thereafter)
    // [12K,17K)  perm1,perm2,maskp1,maskp2,id256 (1 KB each)
    // [17K,+128) kpar1,kpar2 (16 ints each)
    // [20K,..)   Wp1 | Wp2 | xb (reused as h2b)
    char* ws = (char*)d_ws;
    float* gsum1  = (float*)ws;
    float* gsq1   = gsum1 + 256;
    float* gsum2  = gsq1 + 256;
    float* gsq2   = gsum2 + 256;
    float* scale1 = gsq2 + 256;
    float* shift1 = scale1 + 256;
    float* scale2 = shift1 + 256;
    float* shift2 = scale2 + 256;
    u16*   zeropad = (u16*)(ws + 8192);
    int*   perm1  = (int*)(ws + 12288);
    int*   perm2  = (int*)(ws + 13312);
    float* maskp1 = (float*)(ws + 14336);
    float* maskp2 = (float*)(ws + 15360);
    int*   id256  = (int*)(ws + 16384);
    int*   kpar1  = (int*)(ws + 17408);
    int*   kpar2  = (int*)(ws + 17472);
    u16* Wp1 = (u16*)(ws + 20480);
    u16* Wp2 = Wp1 + 9 * 256 * 256;
    u16* xb  = Wp2 + 9 * 256 * 256;
    u16* h2b = xb;                          // xb dead after conv1
    u16* h1b = (u16*)d_out;                 // bf16 scratch inside 102.8 MB output

    zero_accum_kernel<<<dim3(12), dim3(256), 0, stream>>>(gsum1);  // stats+scales+zeropad
    mask_scan_kernel<<<dim3(2), dim3(256), 0, stream>>>(
        mask1, mask2, perm1, perm2, maskp1, maskp2, kpar1, kpar2, id256);
    cvt_x_kernel<<<dim3(N_ * H_), dim3(256), 0, stream>>>(x, xb);
    pack_w_kernel<<<dim3(2304), dim3(256), 0, stream>>>(W1, perm1, id256, Wp1);
    pack_w_kernel<<<dim3(2304), dim3(256), 0, stream>>>(W2, perm2, perm1, Wp2);

    dim3 cgrid(N_ * 56);   // 1792 1-D (pair-local XCD swizzle in-kernel)
    BasicBlock_4355096838467_kernel<<<cgrid, dim3(256), 0, stream>>>(
        xb, Wp1, maskp1, zeropad, kpar1, h1b);
    stats_nhwc_kernel<<<dim3(392), dim3(256), 0, stream>>>(h1b, kpar1, gsum1, gsq1);
    finalize_bn_kernel<<<dim3(1), dim3(256), 0, stream>>>(
        gsum1, gsq1, gamma1, beta1, perm1, scale1, shift1);
    chunk_sel_kernel<<<dim3(1), dim3(256), 0, stream>>>(shift1, kpar1, kpar2);
    bn_relu_nhwc_kernel<<<dim3(12544), dim3(256), 0, stream>>>(h1b, scale1, shift1, kpar1);

    BasicBlock_4355096838467_kernel<<<cgrid, dim3(256), 0, stream>>>(
        h1b, Wp2, maskp2, zeropad, kpar2, h2b);
    stats_nhwc_kernel<<<dim3(392), dim3(256), 0, stream>>>(h2b, kpar2, gsum2, gsq2);
    finalize_bn_kernel<<<dim3(1), dim3(256), 0, stream>>>(
        gsum2, gsq2, gamma2, beta2, perm2, scale2, shift2);
    bn_add_relu_out_kernel<<<dim3(N_ * H_), dim3(256), 0, stream>>>(
        h2b, x, scale2, shift2, perm2, kpar2, out);
}